// Round 3
// baseline (770.332 us; speedup 1.0000x reference)
//
#include <hip/hip_runtime.h>

// BsplineEncoding: N=1M, D=3, K=64, cubic. Row = 195 fp32/point; 780 MB out.
// R2 post-mortem: LDS-assembled single-write got ~2.9 TB/s — store pipe idles
// during the 2 barriers + block turnover (15625 short blocks, 3/CU resident).
// R3: persistent grid (1536 blocks = 6/CU), 16-point tiles, double-buffered
// LDS (2 x 12.2 KB). Stores are issued fire-and-forget at the top of each
// iteration, then the next tile is assembled in the other buffer -> the
// store stream never waits on a barrier.

constexpr int   DIMS        = 3;
constexpr int   K           = 64;
constexpr int   ROW         = DIMS * (1 + K);           // 195 floats
constexpr float SCALE       = 30.5f;                    // (K-3)/2
constexpr float CLAMP_MAX   = 61.0f - 1e-6f;            // K-DEG-EPS
constexpr int   PTS_PER_TILE = 16;
constexpr int   SEGS_PER_TILE = PTS_PER_TILE * DIMS;    // 48 (point,dim) pairs
constexpr int   FLT_PER_TILE = PTS_PER_TILE * ROW;      // 3120 floats = 12.19 KB
constexpr int   V4_PER_TILE  = FLT_PER_TILE / 4;        // 780
constexpr int   NBLOCKS      = 1536;                    // 6 per CU

__device__ __forceinline__ void zero_tile(float4* b4, int t) {
    for (int f = t; f < V4_PER_TILE; f += 256)
        b4[f] = make_float4(0.f, 0.f, 0.f, 0.f);
}

__device__ __forceinline__ void scatter_tile(float* buf, int t, int tile,
                                             const float* __restrict__ x,
                                             int n_points) {
    if (t < SEGS_PER_TILE) {
        const int pt = t / 3;
        const int d  = t - pt * 3;
        const int n  = tile * PTS_PER_TILE + pt;
        if (n < n_points) {
            const float xv = x[(long long)tile * SEGS_PER_TILE + t]; // coalesced
            float xs = (xv + 1.0f) * SCALE;
            xs = fminf(fmaxf(xs, 0.0f), CLAMP_MAX);
            const int   idx = (int)xs;                  // xs >= 0: trunc==floor
            const float u   = xs - (float)idx;
            const float u2  = u * u;
            const float u3  = u2 * u;
            const float om  = 1.0f - u;
            const float c0  = om * om * om * (1.0f / 6.0f);
            const float c1  = (3.0f * u3 - 6.0f * u2 + 4.0f) * (1.0f / 6.0f);
            const float c2  = (-3.0f * u3 + 3.0f * u2 + 3.0f * u + 1.0f) * (1.0f / 6.0f);
            const float c3  = u3 * (1.0f / 6.0f);

            float* seg = buf + pt * ROW + d * (1 + K);
            seg[0] = xv;
            float* fp = seg + 1 + idx;
            fp[0] = c0; fp[1] = c1; fp[2] = c2; fp[3] = c3;
        }
    }
}

__device__ __forceinline__ void store_tile(const float4* b4, int t, int tile,
                                           float4* __restrict__ out4) {
    float4* dst = out4 + (long long)tile * V4_PER_TILE;
    for (int f = t; f < V4_PER_TILE; f += 256)
        dst[f] = b4[f];            // fire-and-forget; never waited on
}

__global__ __launch_bounds__(256)
void bspline_kernel(const float* __restrict__ x, float* __restrict__ out,
                    int n_points, int n_tiles) {
    __shared__ __align__(16) float lds[2][FLT_PER_TILE];
    const int t = threadIdx.x;
    float4* out4 = reinterpret_cast<float4*>(out);

    int tile = blockIdx.x;
    if (tile >= n_tiles) return;

    // Prologue: assemble first tile into buf 0.
    zero_tile(reinterpret_cast<float4*>(lds[0]), t);
    __syncthreads();
    scatter_tile(lds[0], t, tile, x, n_points);
    __syncthreads();

    int p = 0;
    for (; tile < n_tiles; tile += NBLOCKS) {
        // 1) Stream assembled tile out (ds_read -> reg -> global_store).
        store_tile(reinterpret_cast<const float4*>(lds[p]), t, tile, out4);

        // 2) Prep next tile in the other buffer while stores drain.
        const int next = tile + NBLOCKS;
        if (next < n_tiles) {
            zero_tile(reinterpret_cast<float4*>(lds[p ^ 1]), t);
        }
        __syncthreads();   // all reads of buf p done; buf p^1 zeroed
        if (next < n_tiles) {
            scatter_tile(lds[p ^ 1], t, next, x, n_points);
        }
        __syncthreads();   // buf p^1 fully assembled
        p ^= 1;
    }
}

extern "C" void kernel_launch(void* const* d_in, const int* in_sizes, int n_in,
                              void* d_out, int out_size, void* d_ws, size_t ws_size,
                              hipStream_t stream) {
    const float* x  = (const float*)d_in[0];
    float* out      = (float*)d_out;
    const int n_pts  = in_sizes[0] / DIMS;                          // 1,000,000
    const int n_tiles = (n_pts + PTS_PER_TILE - 1) / PTS_PER_TILE;  // 62,500
    bspline_kernel<<<dim3(NBLOCKS), dim3(256), 0, stream>>>(x, out, n_pts, n_tiles);
}